// Round 8
// baseline (988.023 us; speedup 1.0000x reference)
//
#include <hip/hip_runtime.h>

#define B_ 512
#define T_ 512

typedef __bf16 bf16x8 __attribute__((ext_vector_type(8)));
typedef float  f32x4  __attribute__((ext_vector_type(4)));
using u16 = unsigned short;

__device__ __forceinline__ float fast_rcp(float x) { return __builtin_amdgcn_rcpf(x); }
__device__ __forceinline__ float sigf(float x)     { return fast_rcp(1.0f + __expf(-x)); }
__device__ __forceinline__ float tanhfast(float x) { return 1.0f - 2.0f * fast_rcp(__expf(2.0f * x) + 1.0f); }

// fp32 -> bf16 RNE
__device__ __forceinline__ u16 f2bf(float f) {
    unsigned u = __float_as_uint(f);
    u += 0x7FFFu + ((u >> 16) & 1u);
    return (u16)(u >> 16);
}

// Light barrier: orders LDS only; global stores stay in flight across ticks.
__device__ __forceinline__ void lbar() {
    asm volatile("s_waitcnt lgkmcnt(0)\n\ts_barrier" ::: "memory");
}

// DPP move, row_shr:N (ctrl 0x110|N): dst lane i <- src lane i-N within each
// 16-lane row (canonical DPP prefix-sum direction; field-verified in R6 with
// N=8); bound_ctrl zeros lanes with i-N < row start.
template<int CTRL>
__device__ __forceinline__ float dppq(float v) {
    int r = __builtin_amdgcn_update_dpp(0, __float_as_int(v), CTRL, 0xF, 0xF, true);
    return __int_as_float(r);
}

// Staging stride for L3 f32 output tile (4 rows x 128 units): 132 -> spread
// banks, 16B-aligned rows for dwordx4 flush.
constexpr int OSTR = 132;

// One LSTM layer, swapped-operand MFMA + QUAD-packed tiles (field-verified
// pair-merge in R6, extended 2->4). acc_s = mfma(W_tile(bt+s), x) gives
// D[gatecol, batch]; lane (q=lane>>4, cc=lane&15) then needs gates of unit
// uE = (bt + cc>>2)*4 + q for batch row cc&3. Merge: tiles 1..3's rows
// (source lanes cc 0..3) are shifted to lane groups 4-7 / 8-11 / 12-15 via
// row_shr:4/8/12, selected by a 2-level cndmask tree. All 64 lanes end up
// computing gates for a real (row, unit). 4-row blocks: LDS rows 4..15 zero.
template<int D, int H, int DSS, bool GOUT>
struct LL {
    static constexpr int K    = D + H;
    static constexpr int KF   = (K + 31) / 32;
    static constexpr int SSTR = KF * 32 + 8;   // u16: 16B-aligned rows, bank-spread

    bf16x8 WB[4][KF];    // weight fragments, 4 tiles of this wave's pack
    float  biasP[4];     // per-lane effective bias (gate 0..3 of unit uE)
    float  cst;          // per-lane c-state for (row cc&3, unit uE)
    int    ownOff;       // LDS u16 offset for own-h write
    int    dnOff;        // LDS offset for downstream write (u16) or stg (f32)
    bool   act;          // wave-uniform

    __device__ __forceinline__ void init(const float* __restrict__ Wih,
                                         const float* __restrict__ Whh,
                                         const float* __restrict__ bih,
                                         const float* __restrict__ bhh,
                                         int lane, int baseTile, bool active) {
        act = active;
        cst = 0.0f;
        const int bt = active ? baseTile : 0;     // keep indices sane when idle
        const int q = lane >> 4, cc = lane & 15;
#pragma unroll
        for (int s = 0; s < 4; ++s) {
            const int nglob = (bt + s) * 16 + cc;   // gatecol, n=4u+g order
            const int u = nglob >> 2, g = nglob & 3;
            const int row = g * H + u;
#pragma unroll
            for (int kf = 0; kf < KF; ++kf) {
                bf16x8 w;
#pragma unroll
                for (int jj = 0; jj < 8; ++jj) {
                    const int k = kf * 32 + q * 8 + jj;
                    float v = 0.0f;
                    if (active) {
                        if (k < D)      v = Wih[row * D + k];
                        else if (k < K) v = Whh[row * H + (k - D)];
                    }
                    w[jj] = (__bf16)v;
                }
                WB[s][kf] = w;
            }
        }
        const int tE = bt + (cc >> 2);
        const int uE = tE * 4 + q;
#pragma unroll
        for (int g2 = 0; g2 < 4; ++g2)
            biasP[g2] = active ? (bih[g2 * H + uE] + bhh[g2 * H + uE]) : 0.0f;
        ownOff = (cc & 3) * SSTR + D + uE;
        dnOff  = (cc & 3) * (GOUT ? OSTR : DSS) + uE;
    }

    // cur: input buffer (x | h_{t-1}); own: buffer receiving h_t (cols D..D+H);
    // down: next layer's x region; stgf: L3 f32 staging tile.
    __device__ __forceinline__ void step(const u16* __restrict__ cur,
                                         u16* __restrict__ own,
                                         u16* __restrict__ down,
                                         float* __restrict__ stgf,
                                         int lane) {
        if (!act) return;
        const int q = lane >> 4, cc = lane & 15;
        bf16x8 A[KF];
#pragma unroll
        for (int kf = 0; kf < KF; ++kf)
            A[kf] = *(const bf16x8*)&cur[cc * SSTR + kf * 32 + q * 8];

        f32x4 a0 = {0.f,0.f,0.f,0.f}, a1 = {0.f,0.f,0.f,0.f};
        f32x4 a2 = {0.f,0.f,0.f,0.f}, a3 = {0.f,0.f,0.f,0.f};
#pragma unroll
        for (int kf = 0; kf < KF; ++kf) {
            a0 = __builtin_amdgcn_mfma_f32_16x16x32_bf16(WB[0][kf], A[kf], a0, 0, 0, 0);
            a1 = __builtin_amdgcn_mfma_f32_16x16x32_bf16(WB[1][kf], A[kf], a1, 0, 0, 0);
            a2 = __builtin_amdgcn_mfma_f32_16x16x32_bf16(WB[2][kf], A[kf], a2, 0, 0, 0);
            a3 = __builtin_amdgcn_mfma_f32_16x16x32_bf16(WB[3][kf], A[kf], a3, 0, 0, 0);
        }

        // quad merge: lane group cc>>2 = 0/1/2/3 takes a0/a1/a2/a3 from lane cc&3
        const bool h4 = lane & 4, h8 = lane & 8;
        float v[4];
#pragma unroll
        for (int r = 0; r < 4; ++r) {
            const float sB = dppq<0x114>(a1[r]);   // row_shr:4
            const float sC = dppq<0x118>(a2[r]);   // row_shr:8
            const float sD = dppq<0x11C>(a3[r]);   // row_shr:12
            const float m0 = h4 ? sB : a0[r];      // valid for cc<8
            const float m1 = h4 ? sD : sC;         // valid for cc>=8
            v[r] = h8 ? m1 : m0;
        }

        const float gi = sigf(v[0] + biasP[0]);
        const float gf = sigf(v[1] + biasP[1]);
        const float gg = tanhfast(v[2] + biasP[2]);
        const float go = sigf(v[3] + biasP[3]);
        const float c  = gf * cst + gi * gg;
        cst = c;
        const float h  = go * tanhfast(c);
        const u16 hb = f2bf(h);

        own[ownOff] = hb;                       // own-h feedback (rows 0..3)
        if constexpr (GOUT) stgf[dnOff] = h;    // f32 staging
        else                down[dnOff] = hb;   // next layer's x
    }
};

// Fused 3-layer pipelined LSTM, 128 blocks x 4 batch rows (2x the CUs of the
// 64-block version; per-SIMD gate VALU ~halved via quad-packing).
// Tick tau: L1 step tau, L2 step tau-1, L3 step tau-2. Parity rule unchanged
// (field-verified): layer at step s reads buf[s&1], writes own-h to
// buf[(s+1)&1], downstream to buf_next[s&1]; one lbar per tick.
constexpr int S1 = 104, S2 = 104, S3 = 200;
constexpr int B1W = 16 * S1, B2W = 16 * S2, B3W = 16 * S3;
constexpr int SMW = 2 * (B1W + B2W + B3W);   // 26112 B

__global__ __launch_bounds__(512, 2)   // 2 waves/EU -> 1 block/CU -> 256 reg/wave
void lstm3_fused(const float* __restrict__ z,
                 const float* __restrict__ Wih1, const float* __restrict__ Whh1,
                 const float* __restrict__ bih1, const float* __restrict__ bhh1,
                 const float* __restrict__ Wih2, const float* __restrict__ Whh2,
                 const float* __restrict__ bih2, const float* __restrict__ bhh2,
                 const float* __restrict__ Wih3, const float* __restrict__ Whh3,
                 const float* __restrict__ bih3, const float* __restrict__ bhh3,
                 float* __restrict__ out, float* __restrict__ hn)
{
    __shared__ u16 smem[SMW];
    __shared__ float stg[2][4][OSTR];          // 4224 B; total LDS ~30 KB
    u16* b1 = smem;
    u16* b2 = smem + 2 * B1W;
    u16* b3 = b2 + 2 * B2W;

    const int tid  = threadIdx.x;
    const int lane = tid & 63;
    const int wvu  = __builtin_amdgcn_readfirstlane(tid >> 6);
    const int b0   = blockIdx.x * 4;

    static_assert(LL<64, 32, S2, false>::SSTR == S1, "S1");
    static_assert(LL<32, 48, S3, false>::SSTR == S2, "S2");
    static_assert(LL<48, 128, 0, true>::SSTR == S3, "S3");

    LL<64, 32, S2, false> l1;   // H=32:  8 tiles = 2 quad-packs -> waves 5,6
    LL<32, 48, S3, false> l2;   // H=48: 12 tiles = 3 quad-packs -> waves 2,3,4
    LL<48, 128, 0, true>  l3;   // H=128:32 tiles = 8 quad-packs -> 1/wave

    l1.init(Wih1, Whh1, bih1, bhh1, lane, 4 * (wvu - 5), (wvu == 5) || (wvu == 6));
    l2.init(Wih2, Whh2, bih2, bhh2, lane, 4 * (wvu - 2), (wvu >= 2) && (wvu <= 4));
    l3.init(Wih3, Whh3, bih3, bhh3, lane, 4 * wvu, true);

    // zero x/h buffers (rows 4-15 and K..KF*32 padding must stay 0)
    for (int i = tid; i < SMW; i += 512) smem[i] = 0;
    lbar();

    // x staging: 4 rows x 32 float2 -> threads 0..127 (waves 0,1 = lightest)
    const int xr = tid >> 5, xp = tid & 31;
    const bool stgx = (tid < 128);
    int xoff = (b0 + xr) * (T_ * 32) + xp;
    if (stgx) {
        const float2 f = ((const float2*)z)[xoff];
        const unsigned pk = (unsigned)f2bf(f.x) | ((unsigned)f2bf(f.y) << 16);
        *(unsigned*)&b1[xr * S1 + 2 * xp] = pk;      // parity 0 = step-0 cur
    }
    xoff += 32;
    lbar();

    const int fr  = tid >> 5;                        // flush row 0..3 (tid<128)
    const int fc4 = (tid & 31) << 2;                 // flush col 0..124 step 4

    for (int tick = 0; tick < T_ + 2; ++tick) {
        const int qq = tick & 1;
        u16* b1c = b1 + qq * B1W;        u16* b1n = b1 + (qq ^ 1) * B1W;
        u16* b2c = b2 + (qq ^ 1) * B2W;  u16* b2n = b2 + qq * B2W;
        u16* b3c = b3 + qq * B3W;        u16* b3n = b3 + (qq ^ 1) * B3W;

        // coalesced flush of L3 output t = tick-3 (staged last tick)
        if (tick >= 3 && stgx) {
            const f32x4 v = *(const f32x4*)&stg[qq ^ 1][fr][fc4];
            *(f32x4*)&out[((size_t)(b0 + fr) * T_ + (tick - 3)) * 128 + fc4] = v;
        }

        // prefetch x_{tick+1}; ds_write at tick end
        unsigned pk = 0;
        const bool hasx = stgx && (tick + 1 < T_);
        if (hasx) {
            const float2 f = ((const float2*)z)[xoff];
            pk = (unsigned)f2bf(f.x) | ((unsigned)f2bf(f.y) << 16);
        }
        xoff += 32;

        if (tick < T_)
            l1.step(b1c, b1n, b2n, nullptr, lane);
        if (tick >= 1 && tick <= T_)
            l2.step(b2c, b2n, b3n, nullptr, lane);
        if (tick >= 2)
            l3.step(b3c, b3n, nullptr, &stg[qq][0][0], lane);

        if (hasx) *(unsigned*)&b1n[xr * S1 + 2 * xp] = pk;
        lbar();
    }

    // epilogue: flush t = T_-1 (parity (T_+1)&1) + h_n (f32)
    if (stgx) {
        const f32x4 v = *(const f32x4*)&stg[(T_ + 1) & 1][fr][fc4];
        *(f32x4*)&out[((size_t)(b0 + fr) * T_ + (T_ - 1)) * 128 + fc4] = v;
        *(f32x4*)&hn[(size_t)(b0 + fr) * 128 + fc4] = v;
    }
}

extern "C" void kernel_launch(void* const* d_in, const int* in_sizes, int n_in,
                              void* d_out, int out_size, void* d_ws, size_t ws_size,
                              hipStream_t stream)
{
    (void)in_sizes; (void)n_in; (void)out_size; (void)d_ws; (void)ws_size;
    const float* z    = (const float*)d_in[0];
    const float* Wih1 = (const float*)d_in[1];
    const float* Whh1 = (const float*)d_in[2];
    const float* bih1 = (const float*)d_in[3];
    const float* bhh1 = (const float*)d_in[4];
    const float* Wih2 = (const float*)d_in[5];
    const float* Whh2 = (const float*)d_in[6];
    const float* bih2 = (const float*)d_in[7];
    const float* bhh2 = (const float*)d_in[8];
    const float* Wih3 = (const float*)d_in[9];
    const float* Whh3 = (const float*)d_in[10];
    const float* bih3 = (const float*)d_in[11];
    const float* bhh3 = (const float*)d_in[12];

    float* out = (float*)d_out;                   // [B,T,128]
    float* hn  = out + (size_t)B_ * T_ * 128;     // [1,B,128]

    hipLaunchKernelGGL(lstm3_fused, dim3(128), dim3(512), 0, stream,
                       z, Wih1, Whh1, bih1, bhh1,
                       Wih2, Whh2, bih2, bhh2,
                       Wih3, Whh3, bih3, bhh3, out, hn);
}

// Round 10
// 697.212 us; speedup vs baseline: 1.4171x; 1.4171x over previous
//
#include <hip/hip_runtime.h>

#define B_ 512
#define T_ 512

typedef __bf16 bf16x8 __attribute__((ext_vector_type(8)));
typedef float  f32x4  __attribute__((ext_vector_type(4)));
using u16 = unsigned short;

__device__ __forceinline__ float fast_rcp(float x) { return __builtin_amdgcn_rcpf(x); }
__device__ __forceinline__ float sigf(float x)     { return fast_rcp(1.0f + __expf(-x)); }
__device__ __forceinline__ float tanhfast(float x) { return 1.0f - 2.0f * fast_rcp(__expf(2.0f * x) + 1.0f); }

// fp32 -> bf16 RNE
__device__ __forceinline__ u16 f2bf(float f) {
    unsigned u = __float_as_uint(f);
    u += 0x7FFFu + ((u >> 16) & 1u);
    return (u16)(u >> 16);
}

// Light barrier: orders LDS only; global stores stay in flight across ticks.
__device__ __forceinline__ void lbar() {
    asm volatile("s_waitcnt lgkmcnt(0)\n\ts_barrier" ::: "memory");
}

// DPP move, row_shr:N (ctrl 0x110|N): dst lane i <- src lane i-N within each
// 16-lane row (field-verified R6 N=8, R8 N=4/8/12); bound_ctrl zeros lanes
// below the row start.
template<int CTRL>
__device__ __forceinline__ float dppq(float v) {
    int r = __builtin_amdgcn_update_dpp(0, __float_as_int(v), CTRL, 0xF, 0xF, true);
    return __int_as_float(r);
}

constexpr int OSTR = 132;   // f32 staging stride (128+4): bank-spread, 16B rows

// One LSTM layer, swapped-operand MFMA + QUAD-packed tiles (field-verified
// R8). acc_s = mfma(W_tile, x) -> D[gatecol, batch]; lane (q,cc) after the
// row_shr:4/8/12 merge holds gates i,f,g,o of unit (bt + cc>>2)*4+q for batch
// row cc&3. NPK packs share the same A-fragments. Each LL instance is only
// constructed inside its wave-group's branch => register cost is per-path,
// not the union (kills the AGPR shuttle seen through R8).
template<int D, int H, int NPK, int DSS, bool GOUT>
struct LL {
    static constexpr int K    = D + H;
    static constexpr int KF   = (K + 31) / 32;
    static constexpr int SSTR = KF * 32 + 8;   // u16: 16B-aligned rows

    bf16x8 WB[NPK][4][KF];
    float  biasP[NPK][4];
    float  cst[NPK];
    int    ownOff[NPK];
    int    dnOff[NPK];

    __device__ __forceinline__ void init(const float* __restrict__ Wih,
                                         const float* __restrict__ Whh,
                                         const float* __restrict__ bih,
                                         const float* __restrict__ bhh,
                                         int lane, int baseTile) {
        const int q = lane >> 4, cc = lane & 15;
#pragma unroll
        for (int p = 0; p < NPK; ++p) {
            cst[p] = 0.0f;
#pragma unroll
            for (int s = 0; s < 4; ++s) {
                const int nglob = (baseTile + 4 * p + s) * 16 + cc;  // n=4u+g
                const int u = nglob >> 2, g = nglob & 3;
                const int row = g * H + u;
#pragma unroll
                for (int kf = 0; kf < KF; ++kf) {
                    bf16x8 w;
#pragma unroll
                    for (int jj = 0; jj < 8; ++jj) {
                        const int k = kf * 32 + q * 8 + jj;
                        float v = 0.0f;
                        if (k < D)      v = Wih[row * D + k];
                        else if (k < K) v = Whh[row * H + (k - D)];
                        w[jj] = (__bf16)v;
                    }
                    WB[p][s][kf] = w;
                }
            }
            const int uE = (baseTile + 4 * p + (cc >> 2)) * 4 + q;
#pragma unroll
            for (int g2 = 0; g2 < 4; ++g2)
                biasP[p][g2] = bih[g2 * H + uE] + bhh[g2 * H + uE];
            ownOff[p] = (cc & 3) * SSTR + D + uE;
            dnOff[p]  = (cc & 3) * (GOUT ? OSTR : DSS) + uE;
        }
    }

    __device__ __forceinline__ void step(const u16* __restrict__ cur,
                                         u16* __restrict__ own,
                                         u16* __restrict__ down,
                                         float* __restrict__ stgf,
                                         int lane) {
        const int q = lane >> 4, cc = lane & 15;
        bf16x8 A[KF];
#pragma unroll
        for (int kf = 0; kf < KF; ++kf)
            A[kf] = *(const bf16x8*)&cur[cc * SSTR + kf * 32 + q * 8];

        const bool h4 = lane & 4, h8 = lane & 8;
#pragma unroll
        for (int p = 0; p < NPK; ++p) {
            f32x4 a0 = {0.f,0.f,0.f,0.f}, a1 = {0.f,0.f,0.f,0.f};
            f32x4 a2 = {0.f,0.f,0.f,0.f}, a3 = {0.f,0.f,0.f,0.f};
#pragma unroll
            for (int kf = 0; kf < KF; ++kf) {
                a0 = __builtin_amdgcn_mfma_f32_16x16x32_bf16(WB[p][0][kf], A[kf], a0, 0, 0, 0);
                a1 = __builtin_amdgcn_mfma_f32_16x16x32_bf16(WB[p][1][kf], A[kf], a1, 0, 0, 0);
                a2 = __builtin_amdgcn_mfma_f32_16x16x32_bf16(WB[p][2][kf], A[kf], a2, 0, 0, 0);
                a3 = __builtin_amdgcn_mfma_f32_16x16x32_bf16(WB[p][3][kf], A[kf], a3, 0, 0, 0);
            }
            float v[4];
#pragma unroll
            for (int r = 0; r < 4; ++r) {
                const float sB = dppq<0x114>(a1[r]);   // row_shr:4
                const float sC = dppq<0x118>(a2[r]);   // row_shr:8
                const float sD = dppq<0x11C>(a3[r]);   // row_shr:12
                const float m0 = h4 ? sB : a0[r];
                const float m1 = h4 ? sD : sC;
                v[r] = h8 ? m1 : m0;
            }
            const float gi = sigf(v[0] + biasP[p][0]);
            const float gf = sigf(v[1] + biasP[p][1]);
            const float gg = tanhfast(v[2] + biasP[p][2]);
            const float go = sigf(v[3] + biasP[p][3]);
            const float c  = gf * cst[p] + gi * gg;
            cst[p] = c;
            const float h  = go * tanhfast(c);
            const u16 hb = f2bf(h);

            own[ownOff[p]] = hb;
            if constexpr (GOUT) stgf[dnOff[p]] = h;
            else                down[dnOff[p]] = hb;
        }
    }
};

// Fused 3-layer pipelined LSTM, 128 blocks x 4 batch rows, 12 waves,
// WAVE-SPECIALIZED by layer (each wave's path holds ONE layer's registers):
//   waves 0-7 : l3 quad-pack #wvu          (~155 regs)
//   waves 8-10: l2 quad-pack #(wvu-8)      (~105 regs; waves 8-9 also do
//               x-staging + coalesced output flush)
//   wave 11   : l1 packs 0+1 (shared A)    (~150 regs)
// Every path executes exactly one lbar per tick -> block barrier stays legal.
// Parity rule (field-verified): layer at step s reads buf[s&1], writes own-h
// to buf[(s+1)&1], downstream to buf_next[s&1].
constexpr int S1 = 104, S2 = 104, S3 = 200;
constexpr int B1W = 16 * S1, B2W = 16 * S2, B3W = 16 * S3;
constexpr int SMW = 2 * (B1W + B2W + B3W);   // 26112 B

__global__ __launch_bounds__(768, 3)   // 3 waves/EU -> VGPR cap ~168, 1 blk/CU
void lstm3_fused(const float* __restrict__ z,
                 const float* __restrict__ Wih1, const float* __restrict__ Whh1,
                 const float* __restrict__ bih1, const float* __restrict__ bhh1,
                 const float* __restrict__ Wih2, const float* __restrict__ Whh2,
                 const float* __restrict__ bih2, const float* __restrict__ bhh2,
                 const float* __restrict__ Wih3, const float* __restrict__ Whh3,
                 const float* __restrict__ bih3, const float* __restrict__ bhh3,
                 float* __restrict__ out, float* __restrict__ hn)
{
    __shared__ u16 smem[SMW];
    __shared__ float stg[2][4][OSTR];          // 4224 B; total LDS ~30 KB
    u16* b1 = smem;
    u16* b2 = smem + 2 * B1W;
    u16* b3 = b2 + 2 * B2W;

    const int tid  = threadIdx.x;
    const int lane = tid & 63;
    const int wvu  = __builtin_amdgcn_readfirstlane(tid >> 6);
    const int b0   = blockIdx.x * 4;

    static_assert(LL<64, 32, 2, S2, false>::SSTR == S1, "S1");
    static_assert(LL<32, 48, 1, S3, false>::SSTR == S2, "S2");
    static_assert(LL<48, 128, 1, 0, true>::SSTR == S3, "S3");

    // zero x/h buffers (rows 4-15 and K..KF*32 padding must stay 0)
    for (int i = tid; i < SMW; i += 768) smem[i] = 0;
    lbar();

    // x_0 staging: waves 8-9 (tid 512..639): 4 rows x 32 float2
    const int xr = (tid >> 5) & 3, xp = tid & 31;
    const bool stgx = (tid >= 512) && (tid < 640);
    int xoff = (b0 + xr) * (T_ * 32) + xp;
    if (stgx) {
        const float2 f = ((const float2*)z)[xoff];
        const unsigned pk = (unsigned)f2bf(f.x) | ((unsigned)f2bf(f.y) << 16);
        *(unsigned*)&b1[xr * S1 + 2 * xp] = pk;      // parity 0 = step-0 cur
    }
    xoff += 32;
    lbar();

    if (wvu < 8) {
        // ---------------- L3 path: one quad-pack, stage f32 h ----------------
        LL<48, 128, 1, 0, true> l3;
        l3.init(Wih3, Whh3, bih3, bhh3, lane, 4 * wvu);
        for (int tick = 0; tick < T_ + 2; ++tick) {
            const int qq = tick & 1;
            u16* b3c = b3 + qq * B3W;
            u16* b3n = b3 + (qq ^ 1) * B3W;
            if (tick >= 2)
                l3.step(b3c, b3n, nullptr, &stg[qq][0][0], lane);
            lbar();
        }
    } else if (wvu < 11) {
        // -------- L2 path: one quad-pack + staging/flush on waves 8-9 --------
        LL<32, 48, 1, S3, false> l2;
        l2.init(Wih2, Whh2, bih2, bhh2, lane, 4 * (wvu - 8));
        const int fc4 = xp << 2;                     // flush col 0..124 step 4
        for (int tick = 0; tick < T_ + 2; ++tick) {
            const int qq = tick & 1;
            u16* b2c = b2 + (qq ^ 1) * B2W;
            u16* b2n = b2 + qq * B2W;
            u16* b3n = b3 + (qq ^ 1) * B3W;
            // coalesced flush of L3 output t = tick-3 (staged last tick)
            if (tick >= 3 && stgx) {
                const f32x4 v = *(const f32x4*)&stg[qq ^ 1][xr][fc4];
                *(f32x4*)&out[((size_t)(b0 + xr) * T_ + (tick - 3)) * 128 + fc4] = v;
            }
            // prefetch x_{tick+1}; ds_write just before the barrier
            unsigned pk = 0;
            const bool hasx = stgx && (tick + 1 < T_);
            if (hasx) {
                const float2 f = ((const float2*)z)[xoff];
                pk = (unsigned)f2bf(f.x) | ((unsigned)f2bf(f.y) << 16);
            }
            xoff += 32;
            if (tick >= 1 && tick <= T_)
                l2.step(b2c, b2n, b3n, nullptr, lane);
            if (hasx)
                *(unsigned*)&(b1 + (qq ^ 1) * B1W)[xr * S1 + 2 * xp] = pk;
            lbar();
        }
        // epilogue: flush t = T_-1 (parity (T_+1)&1) + h_n (f32)
        if (stgx) {
            const f32x4 v = *(const f32x4*)&stg[(T_ + 1) & 1][xr][fc4];
            *(f32x4*)&out[((size_t)(b0 + xr) * T_ + (T_ - 1)) * 128 + fc4] = v;
            *(f32x4*)&hn[(size_t)(b0 + xr) * 128 + fc4] = v;
        }
    } else {
        // ---------------- L1 path: two quad-packs (shared A) ----------------
        LL<64, 32, 2, S2, false> l1;
        l1.init(Wih1, Whh1, bih1, bhh1, lane, 0);
        for (int tick = 0; tick < T_ + 2; ++tick) {
            const int qq = tick & 1;
            u16* b1c = b1 + qq * B1W;
            u16* b1n = b1 + (qq ^ 1) * B1W;
            u16* b2n = b2 + qq * B2W;
            if (tick < T_)
                l1.step(b1c, b1n, b2n, nullptr, lane);
            lbar();
        }
    }
}

extern "C" void kernel_launch(void* const* d_in, const int* in_sizes, int n_in,
                              void* d_out, int out_size, void* d_ws, size_t ws_size,
                              hipStream_t stream)
{
    (void)in_sizes; (void)n_in; (void)out_size; (void)d_ws; (void)ws_size;
    const float* z    = (const float*)d_in[0];
    const float* Wih1 = (const float*)d_in[1];
    const float* Whh1 = (const float*)d_in[2];
    const float* bih1 = (const float*)d_in[3];
    const float* bhh1 = (const float*)d_in[4];
    const float* Wih2 = (const float*)d_in[5];
    const float* Whh2 = (const float*)d_in[6];
    const float* bih2 = (const float*)d_in[7];
    const float* bhh2 = (const float*)d_in[8];
    const float* Wih3 = (const float*)d_in[9];
    const float* Whh3 = (const float*)d_in[10];
    const float* bih3 = (const float*)d_in[11];
    const float* bhh3 = (const float*)d_in[12];

    float* out = (float*)d_out;                   // [B,T,128]
    float* hn  = out + (size_t)B_ * T_ * 128;     // [1,B,128]

    hipLaunchKernelGGL(lstm3_fused, dim3(128), dim3(768), 0, stream,
                       z, Wih1, Whh1, bih1, bhh1,
                       Wih2, Whh2, bih2, bhh2,
                       Wih3, Whh3, bih3, bhh3, out, hn);
}